// Round 18
// baseline (195.871 us; speedup 1.0000x reference)
//
#include <hip/hip_runtime.h>
#include <hip/hip_bf16.h>

// DEC ClusteringLayer: q[i][j] = (1/(1+||x_i-c_j||^2)) / rowsum, ALPHA=1.
// Round 18 = R17 with the buffer-recycle race fixed: B prefetch distance is
// now 1 (dbuf-safe; G(J+1) writes buf (J+1)&1 while MSTEP(J) reads buf J&1).
// B is L2-resident (~300-600cy) and one BM=128 MSTEP is ~2000+cy -> 1-iter
// cover suffices; A (HBM) keeps 2-iter cover via the X register pair.
// Single kernel (no prep): B gathered straight from fp32 clusters via
// global_load_lds with inverse-swizzle baked into per-lane source addresses
// (rule #21); cvt fp32->bf16 at LDS-read; ||c||^2 fused into the B reads.

typedef __attribute__((ext_vector_type(8))) short short8v;
typedef __attribute__((ext_vector_type(4))) float f32x4;

#define DDIM 512
#define KCL  256
#define BM   128
#define NT   512
#define NTILES 16

__device__ __forceinline__ short f2bf(float f) {
    __hip_bfloat16 h = __float2bfloat16(f);
    return __builtin_bit_cast(short, h);
}

__device__ __forceinline__ void glds16(const void* g, void* l) {
    __builtin_amdgcn_global_load_lds(
        (const __attribute__((address_space(1))) unsigned int*)g,
        (__attribute__((address_space(3))) unsigned int*)l, 16, 0, 0);
}

#define SFENCE() __builtin_amdgcn_sched_barrier(0)
#define BARV2()  asm volatile("s_waitcnt vmcnt(2) lgkmcnt(0)\ns_barrier" ::: "memory")
#define BARV0()  asm volatile("s_waitcnt vmcnt(0) lgkmcnt(0)\ns_barrier" ::: "memory")

__global__ __launch_bounds__(NT, 4)
void dec_main(const float* __restrict__ x, const float* __restrict__ cl,
              float* __restrict__ out) {
    __shared__ __align__(16) short lA[2][4096];    // 16 KB: A bf16 frag-order dbuf
    __shared__ __align__(16) float lBf[2][8192];   // 64 KB: B fp32 swizzled dbuf
    float* const s_x2 = (float*)&lA[0][0];         // aliased post-loop (3.5 KB)
    float* const s_rs = (float*)&lA[0][0] + BM;
    float* const s_c2 = (float*)&lA[0][0] + BM + 4*BM;

    const int t = threadIdx.x, lane = t & 63, w = t >> 6;
    const int rg = w >> 2, cg = w & 3;             // 2 row-groups x 4 col-groups
    const int l15 = lane & 15, lq = lane >> 4;
    const int row0 = blockIdx.x * BM;

    // ---- A staging (R11 verbatim): thread covers row R=t>>2, 8 floats at (t&3)*8
    const int R = t >> 2, q = t & 3;
    const float* xs = x + (size_t)(row0 + R) * DDIM + q * 8;
    const int awr  = ((R >> 4) * 64 + (((R & 15) ^ (2 * q)) + 16 * q)) * 8;
    const int aoff = (((l15 ^ (2 * lq)) + 16 * lq)) * 8;

    // ---- B DMA source decode: slot s = t + r*512 (16B slots, 2048/image) ----
    // s bits: c'=s&7, l15s=(s>>3)&15, nb=s>>7 ; actual chunk c = c'^(l15s&7);
    // col = nb*16+l15s ; k-in-image = (c>>1)*8 + (c&1)*4.
    int boff[4];
#pragma unroll
    for (int r = 0; r < 4; ++r) {
        const int s  = t + r * 512;
        const int cc = (s & 7) ^ ((s >> 3) & 7);
        const int col = ((s >> 7) << 4) + ((s >> 3) & 15);
        boff[r] = col * DDIM + ((cc >> 1) << 3) + ((cc & 1) << 2);
    }
    // B read slots (swizzled): even chunk of frag nb at slot nb*128+bo0, odd at ^1
    const int bo0 = l15 * 8 + ((lq * 2) ^ (l15 & 7));

    f32x4 acc[4][4];
#pragma unroll
    for (int m = 0; m < 4; ++m)
#pragma unroll
        for (int n = 0; n < 4; ++n) acc[m][n] = (f32x4){0.f,0.f,0.f,0.f};
    float x2p = 0.f;
    float c2p[4] = {0.f, 0.f, 0.f, 0.f};
    float4 XA0, XA1, XB0, XB1;

#define GLDSB(TT, P)                                                 \
    {  const float* im_ = cl + (TT) * 32;                            \
       glds16(im_ + boff[0], &lBf[P][t * 4]);                        \
       glds16(im_ + boff[1], &lBf[P][t * 4 + 2048]);                 \
       glds16(im_ + boff[2], &lBf[P][t * 4 + 4096]);                 \
       glds16(im_ + boff[3], &lBf[P][t * 4 + 6144]); }

#define LOADX(TT, X0R, X1R)                                  \
    {  X0R = *(const float4*)(xs + (TT) * 32);               \
       X1R = *(const float4*)(xs + (TT) * 32 + 4); }

#define CVT(X0R, X1R, ABN)                                                       \
    {  short8v s_;                                                               \
       s_[0]=f2bf(X0R.x); s_[1]=f2bf(X0R.y); s_[2]=f2bf(X0R.z); s_[3]=f2bf(X0R.w);\
       s_[4]=f2bf(X1R.x); s_[5]=f2bf(X1R.y); s_[6]=f2bf(X1R.z); s_[7]=f2bf(X1R.w);\
       x2p += X0R.x*X0R.x + X0R.y*X0R.y + X0R.z*X0R.z + X0R.w*X0R.w              \
            + X1R.x*X1R.x + X1R.y*X1R.y + X1R.z*X1R.z + X1R.w*X1R.w;             \
       *(short8v*)&lA[ABN][awr] = s_; }

#define MSTEP(ABN, BP)                                                           \
    {  short8v a0 = *(const short8v*)&lA[ABN][(rg*4+0)*512 + aoff];              \
       short8v a1 = *(const short8v*)&lA[ABN][(rg*4+1)*512 + aoff];              \
       short8v a2 = *(const short8v*)&lA[ABN][(rg*4+2)*512 + aoff];              \
       short8v a3 = *(const short8v*)&lA[ABN][(rg*4+3)*512 + aoff];              \
       _Pragma("unroll")                                                         \
       for (int n = 0; n < 4; ++n) {                                             \
           const int s0 = (cg*4 + n) * 128 + bo0;                                \
           float4 blo = *(const float4*)&lBf[BP][s0 * 4];                        \
           float4 bhi = *(const float4*)&lBf[BP][(s0 ^ 1) * 4];                  \
           short8v bf_;                                                          \
           bf_[0]=f2bf(blo.x); bf_[1]=f2bf(blo.y); bf_[2]=f2bf(blo.z); bf_[3]=f2bf(blo.w); \
           bf_[4]=f2bf(bhi.x); bf_[5]=f2bf(bhi.y); bf_[6]=f2bf(bhi.z); bf_[7]=f2bf(bhi.w); \
           if (rg == 0)                                                          \
               c2p[n] += blo.x*blo.x + blo.y*blo.y + blo.z*blo.z + blo.w*blo.w   \
                       + bhi.x*bhi.x + bhi.y*bhi.y + bhi.z*bhi.z + bhi.w*bhi.w;  \
           acc[0][n] = __builtin_amdgcn_mfma_f32_16x16x32_bf16(a0, bf_, acc[0][n], 0,0,0); \
           acc[1][n] = __builtin_amdgcn_mfma_f32_16x16x32_bf16(a1, bf_, acc[1][n], 0,0,0); \
           acc[2][n] = __builtin_amdgcn_mfma_f32_16x16x32_bf16(a2, bf_, acc[2][n], 0,0,0); \
           acc[3][n] = __builtin_amdgcn_mfma_f32_16x16x32_bf16(a3, bf_, acc[3][n], 0,0,0); \
       } }

    // ITER(J): entering queue = {X(J+1)}. Issue X(J+2) then G(J+1) -> buf
    // (J+1)&1 (!= read buf J&1: race-free). CVT(X(J+1)) auto-drains X(J+1)
    // (oldest). MSTEP(J). Barrier vmcnt(2) drains G(J+1), leaves X(J+2).
#define ITER(J, ABC, ABN, XC0, XC1, XL0, XL1)                                    \
    {  if ((J) + 2 < NTILES) { LOADX((J) + 2, XL0, XL1); }                       \
       SFENCE();                                                                 \
       if ((J) + 1 < NTILES) { GLDSB((J) + 1, ((J) + 1) & 1); }                  \
       SFENCE();                                                                 \
       if ((J) + 1 < NTILES) { CVT(XC0, XC1, ABN); }                             \
       MSTEP(ABC, (J) & 1);                                                      \
       SFENCE();                                                                 \
       if ((J) + 2 < NTILES) { BARV2(); }                                        \
       else if ((J) + 1 < NTILES) { BARV0(); }                                   \
       SFENCE(); }

    // ---- prologue: X(0); G(0); X(1); cvt X(0); barrier vmcnt(2) ----
    LOADX(0, XA0, XA1);  SFENCE();
    GLDSB(0, 0);         SFENCE();
    LOADX(1, XB0, XB1);  SFENCE();
    CVT(XA0, XA1, 0);        // implicit wait drains only X(0) (oldest)
    SFENCE();
    BARV2();                 // drains G(0); leaves X(1) in flight
    SFENCE();

    ITER( 0, 0, 1, XB0, XB1, XA0, XA1)
    ITER( 1, 1, 0, XA0, XA1, XB0, XB1)
    ITER( 2, 0, 1, XB0, XB1, XA0, XA1)
    ITER( 3, 1, 0, XA0, XA1, XB0, XB1)
    ITER( 4, 0, 1, XB0, XB1, XA0, XA1)
    ITER( 5, 1, 0, XA0, XA1, XB0, XB1)
    ITER( 6, 0, 1, XB0, XB1, XA0, XA1)
    ITER( 7, 1, 0, XA0, XA1, XB0, XB1)
    ITER( 8, 0, 1, XB0, XB1, XA0, XA1)
    ITER( 9, 1, 0, XA0, XA1, XB0, XB1)
    ITER(10, 0, 1, XB0, XB1, XA0, XA1)
    ITER(11, 1, 0, XA0, XA1, XB0, XB1)
    ITER(12, 0, 1, XB0, XB1, XA0, XA1)
    ITER(13, 1, 0, XA0, XA1, XB0, XB1)
    ITER(14, 0, 1, XB0, XB1, XA0, XA1)
    ITER(15, 1, 0, XA0, XA1, XB0, XB1)   // MSTEP only

    __syncthreads();   // all lA/lBf reads done; aliases live from here

    // ---- ||x||^2: 4 staging threads per row ----
    x2p += __shfl_xor(x2p, 1); x2p += __shfl_xor(x2p, 2);
    if (q == 0) s_x2[R] = x2p;

    // ---- ||c||^2: rg==0 lanes hold per-(col,lq) partials; reduce over lq ----
#pragma unroll
    for (int n = 0; n < 4; ++n) {
        float v = c2p[n];
        v += __shfl_xor(v, 16); v += __shfl_xor(v, 32);
        if (rg == 0 && lq == 0) s_c2[cg*64 + n*16 + l15] = v;
    }
    __syncthreads();

    // ---- epilogue: d2 -> q_unnorm (C/D: col=l15, row=lq*4+r) ----
    float c2a[4];
#pragma unroll
    for (int n = 0; n < 4; ++n) c2a[n] = s_c2[cg*64 + n*16 + l15];

#pragma unroll
    for (int m = 0; m < 4; ++m)
#pragma unroll
        for (int n = 0; n < 4; ++n)
#pragma unroll
            for (int r = 0; r < 4; ++r) {
                const int rw = rg*64 + m*16 + lq*4 + r;
                float d2 = fmaxf(s_x2[rw] + c2a[n] - 2.0f * acc[m][n][r], 0.0f);
                acc[m][n][r] = 1.0f / (1.0f + d2);
            }

    // ---- row sums: 16-lane shuffle, per-cg slot (deterministic) ----
#pragma unroll
    for (int m = 0; m < 4; ++m)
#pragma unroll
        for (int r = 0; r < 4; ++r) {
            float p = acc[m][0][r] + acc[m][1][r] + acc[m][2][r] + acc[m][3][r];
            p += __shfl_xor(p, 1); p += __shfl_xor(p, 2);
            p += __shfl_xor(p, 4); p += __shfl_xor(p, 8);
            if (l15 == 0) s_rs[cg*BM + rg*64 + m*16 + lq*4 + r] = p;
        }
    __syncthreads();

    // ---- normalize + store ----
#pragma unroll
    for (int m = 0; m < 4; ++m)
#pragma unroll
        for (int r = 0; r < 4; ++r) {
            const int rw = rg*64 + m*16 + lq*4 + r;
            const float rinv = 1.0f / (s_rs[rw] + s_rs[BM + rw]
                                     + s_rs[2*BM + rw] + s_rs[3*BM + rw]);
            float* o = out + (size_t)(row0 + rw) * KCL + cg*64 + l15;
#pragma unroll
            for (int n = 0; n < 4; ++n)
                o[n * 16] = acc[m][n][r] * rinv;
        }
}

extern "C" void kernel_launch(void* const* d_in, const int* in_sizes, int n_in,
                              void* d_out, int out_size, void* d_ws, size_t ws_size,
                              hipStream_t stream) {
    const float* x  = (const float*)d_in[0];
    const float* cl = (const float*)d_in[1];
    float* out = (float*)d_out;
    const int B = in_sizes[0] / DDIM;     // 65536
    dec_main<<<B / BM, NT, 0, stream>>>(x, cl, out);
}

// Round 19
// 49.006 us; speedup vs baseline: 3.9969x; 3.9969x over previous
//
#include <hip/hip_runtime.h>
#include <hip/hip_bf16.h>

// DEC ClusteringLayer: q[i][j] = (1/(1+||x_i-c_j||^2)) / rowsum, ALPHA=1.
// FINAL = Round 11 verbatim (measured best, 49.4us). BM=128: per wave 64x64
// output (acc[4][4]); 16 MFMA per 8 LDS reads; 512 blocks; 1 barrier/iter.
// Queue discipline: X issued BEFORE GLDS, so CVT's implicit X-wait drains only
// a 2-iter-old X; barrier vmcnt(4) waits on a 1-iter-old B-DMA, leaving the
// younger X+GLDS pair in flight. B tri-buffered (race-free at 2-ahead).
// A-LDS XOR-swizzle ((R&15)^(2q))+16q: write AND read conflict-free.
// Rounds 12-18 nulled: work/barrier x2 (spill), 3-4 blocks/CU (-22%/tie),
// deeper cover (tie), phase-split+setprio (-18%, regime-gated), prep-fusion
// (race/spill). ~49-51us is this shape's structural plateau.

typedef __attribute__((ext_vector_type(8))) short short8v;
typedef __attribute__((ext_vector_type(4))) float f32x4;

#define DDIM 512
#define KCL  256
#define BM   128
#define NT   512
#define NTILES 16
#define BTILE  8192      // shorts per fragment-order B image (256 x 32)

__device__ __forceinline__ short f2bf(float f) {
    __hip_bfloat16 h = __float2bfloat16(f);
    return __builtin_bit_cast(short, h);
}

__device__ __forceinline__ void glds16(const void* g, void* l) {
    __builtin_amdgcn_global_load_lds(
        (const __attribute__((address_space(1))) unsigned int*)g,
        (__attribute__((address_space(3))) unsigned int*)l, 16, 0, 0);
}

// ---- pre-kernel: blocks 0..63 pack clusters -> bf16 fragment-order images;
//      blocks 64..79 compute ||c||^2 ----
__global__ void prep(const float* __restrict__ cl, short* __restrict__ wsB,
                     float* __restrict__ wsC2) {
    const int t = threadIdx.x;
    if (blockIdx.x < 64) {
        const int u = blockIdx.x * 256 + t;
        const int img = u >> 10, gi = u & 1023;
        const int g = gi >> 6, lq = (gi >> 4) & 3, l15 = gi & 15;
        const float* src = cl + (size_t)(g * 16 + l15) * DDIM + img * 32 + lq * 8;
        float4 a = *(const float4*)src;
        float4 b = *(const float4*)(src + 4);
        short8v s;
        s[0]=f2bf(a.x); s[1]=f2bf(a.y); s[2]=f2bf(a.z); s[3]=f2bf(a.w);
        s[4]=f2bf(b.x); s[5]=f2bf(b.y); s[6]=f2bf(b.z); s[7]=f2bf(b.w);
        *(short8v*)&wsB[(size_t)u * 8] = s;
    } else {
        const int cidx = (blockIdx.x - 64) * 16 + (t >> 4);
        const int j = t & 15;
        const float* src = cl + (size_t)cidx * DDIM + j * 32;
        float s = 0.f;
#pragma unroll
        for (int i = 0; i < 8; ++i) {
            float4 v = ((const float4*)src)[i];
            s += v.x*v.x + v.y*v.y + v.z*v.z + v.w*v.w;
        }
        s += __shfl_xor(s, 1); s += __shfl_xor(s, 2);
        s += __shfl_xor(s, 4); s += __shfl_xor(s, 8);
        if (j == 0) wsC2[cidx] = s;
    }
}

#define SFENCE() __builtin_amdgcn_sched_barrier(0)
#define BARV4()  asm volatile("s_waitcnt vmcnt(4) lgkmcnt(0)\ns_barrier" ::: "memory")
#define BARV0()  asm volatile("s_waitcnt vmcnt(0) lgkmcnt(0)\ns_barrier" ::: "memory")

__global__ __launch_bounds__(NT, 4)
void dec_main(const float* __restrict__ x, const short* __restrict__ wsB,
              const float* __restrict__ wsC2, float* __restrict__ out) {
    __shared__ __align__(16) short lB3[3][BTILE];   // 48 KB tri-buffered B images
    __shared__ __align__(16) short lA[2][4096];     // 2 x 8 KB fragment-order A tiles
    __shared__ float s_x2[BM];                      // 512 B
    __shared__ float s_rs[4][BM];                   // 2 KB

    const int t = threadIdx.x, lane = t & 63, w = t >> 6;
    const int rg = w >> 2, cg = w & 3;              // 2 row-groups x 4 col-groups
    const int l15 = lane & 15, lq = lane >> 4;
    const int row0 = blockIdx.x * BM;

    // ---- A staging: thread t covers row R=t>>2, 8 floats at cols (t&3)*8 ----
    const int R = t >> 2, q = t & 3;
    const float* xs = x + (size_t)(row0 + R) * DDIM + q * 8;
    // swizzled fragment slot: m-block R>>4, slot ((R&15)^(2q)) + 16q (16B each)
    const int awr = ((R >> 4) * 64 + (((R & 15) ^ (2 * q)) + 16 * q)) * 8;
    // A read offset: lane (l15,lq) -> slot (l15^(2lq)) + 16lq of its m-block
    const int aoff = (((l15 ^ (2 * lq)) + 16 * lq)) * 8;

    const short* bb = wsB;   // B images consumed via GLDS only

    f32x4 acc[4][4];
#pragma unroll
    for (int m = 0; m < 4; ++m)
#pragma unroll
        for (int n = 0; n < 4; ++n) acc[m][n] = (f32x4){0.f,0.f,0.f,0.f};
    float x2p = 0.f;
    float4 XA0, XA1, XB0, XB1;

#define GLDS(TT, LBN)                                        \
    {  const short* src_ = bb + (size_t)(TT) * BTILE;        \
       glds16(src_ + t * 8,        (LBN) + t * 8);           \
       glds16(src_ + 4096 + t * 8, (LBN) + 4096 + t * 8); }

#define LOADX(TT, X0R, X1R)                                  \
    {  X0R = *(const float4*)(xs + (TT) * 32);               \
       X1R = *(const float4*)(xs + (TT) * 32 + 4); }

#define CVT(X0R, X1R, ABN)                                                       \
    {  short8v s_;                                                               \
       s_[0]=f2bf(X0R.x); s_[1]=f2bf(X0R.y); s_[2]=f2bf(X0R.z); s_[3]=f2bf(X0R.w);\
       s_[4]=f2bf(X1R.x); s_[5]=f2bf(X1R.y); s_[6]=f2bf(X1R.z); s_[7]=f2bf(X1R.w);\
       x2p += X0R.x*X0R.x + X0R.y*X0R.y + X0R.z*X0R.z + X0R.w*X0R.w              \
            + X1R.x*X1R.x + X1R.y*X1R.y + X1R.z*X1R.z + X1R.w*X1R.w;             \
       *(short8v*)&lA[ABN][awr] = s_; }

#define MSTEP(ABN, LBN)                                                          \
    {  short8v a0 = *(const short8v*)&lA[ABN][(rg*4+0)*512 + aoff];              \
       short8v a1 = *(const short8v*)&lA[ABN][(rg*4+1)*512 + aoff];              \
       short8v a2 = *(const short8v*)&lA[ABN][(rg*4+2)*512 + aoff];              \
       short8v a3 = *(const short8v*)&lA[ABN][(rg*4+3)*512 + aoff];              \
       short8v b0 = *(const short8v*)&(LBN)[cg*2048 + lane*8];                   \
       short8v b1 = *(const short8v*)&(LBN)[cg*2048 + 512  + lane*8];            \
       short8v b2 = *(const short8v*)&(LBN)[cg*2048 + 1024 + lane*8];            \
       short8v b3 = *(const short8v*)&(LBN)[cg*2048 + 1536 + lane*8];            \
       acc[0][0] = __builtin_amdgcn_mfma_f32_16x16x32_bf16(a0, b0, acc[0][0], 0,0,0); \
       acc[0][1] = __builtin_amdgcn_mfma_f32_16x16x32_bf16(a0, b1, acc[0][1], 0,0,0); \
       acc[0][2] = __builtin_amdgcn_mfma_f32_16x16x32_bf16(a0, b2, acc[0][2], 0,0,0); \
       acc[0][3] = __builtin_amdgcn_mfma_f32_16x16x32_bf16(a0, b3, acc[0][3], 0,0,0); \
       acc[1][0] = __builtin_amdgcn_mfma_f32_16x16x32_bf16(a1, b0, acc[1][0], 0,0,0); \
       acc[1][1] = __builtin_amdgcn_mfma_f32_16x16x32_bf16(a1, b1, acc[1][1], 0,0,0); \
       acc[1][2] = __builtin_amdgcn_mfma_f32_16x16x32_bf16(a1, b2, acc[1][2], 0,0,0); \
       acc[1][3] = __builtin_amdgcn_mfma_f32_16x16x32_bf16(a1, b3, acc[1][3], 0,0,0); \
       acc[2][0] = __builtin_amdgcn_mfma_f32_16x16x32_bf16(a2, b0, acc[2][0], 0,0,0); \
       acc[2][1] = __builtin_amdgcn_mfma_f32_16x16x32_bf16(a2, b1, acc[2][1], 0,0,0); \
       acc[2][2] = __builtin_amdgcn_mfma_f32_16x16x32_bf16(a2, b2, acc[2][2], 0,0,0); \
       acc[2][3] = __builtin_amdgcn_mfma_f32_16x16x32_bf16(a2, b3, acc[2][3], 0,0,0); \
       acc[3][0] = __builtin_amdgcn_mfma_f32_16x16x32_bf16(a3, b0, acc[3][0], 0,0,0); \
       acc[3][1] = __builtin_amdgcn_mfma_f32_16x16x32_bf16(a3, b1, acc[3][1], 0,0,0); \
       acc[3][2] = __builtin_amdgcn_mfma_f32_16x16x32_bf16(a3, b2, acc[3][2], 0,0,0); \
       acc[3][3] = __builtin_amdgcn_mfma_f32_16x16x32_bf16(a3, b3, acc[3][3], 0,0,0); }

    // ITER(J): X(J+2) -> GLDS(J+2) -> CVT(X(J+1)) -> MSTEP(J) -> BARV4.
#define ITER(J, ABC, ABN, BCUR, BNXT, XC0, XC1, XL0, XL1)                        \
    {  if ((J) + 2 < NTILES) { LOADX((J) + 2, XL0, XL1); }                       \
       SFENCE();                                                                 \
       if ((J) + 2 < NTILES) { GLDS((J) + 2, BNXT); }                            \
       SFENCE();                                                                 \
       if ((J) + 1 < NTILES) { CVT(XC0, XC1, ABN); }                             \
       MSTEP(ABC, BCUR);                                                         \
       SFENCE();                                                                 \
       if ((J) + 2 < NTILES) { BARV4(); }                                        \
       else if ((J) + 1 < NTILES) { BARV0(); }                                   \
       SFENCE(); }

    // ---- prologue: X(0); G(0); X(1); G(1); cvt X(0); barrier(vmcnt 4) ----
    LOADX(0, XA0, XA1);  SFENCE();
    GLDS(0, &lB3[0][0]); SFENCE();
    LOADX(1, XB0, XB1);  SFENCE();
    GLDS(1, &lB3[1][0]); SFENCE();
    CVT(XA0, XA1, 0);        // waits only X(0) (oldest)
    SFENCE();
    BARV4();                 // drains G(0); leaves X(1)+G(1) in flight
    SFENCE();

    ITER( 0, 0, 1, &lB3[0][0], &lB3[2][0], XB0, XB1, XA0, XA1)
    ITER( 1, 1, 0, &lB3[1][0], &lB3[0][0], XA0, XA1, XB0, XB1)
    ITER( 2, 0, 1, &lB3[2][0], &lB3[1][0], XB0, XB1, XA0, XA1)
    ITER( 3, 1, 0, &lB3[0][0], &lB3[2][0], XA0, XA1, XB0, XB1)
    ITER( 4, 0, 1, &lB3[1][0], &lB3[0][0], XB0, XB1, XA0, XA1)
    ITER( 5, 1, 0, &lB3[2][0], &lB3[1][0], XA0, XA1, XB0, XB1)
    ITER( 6, 0, 1, &lB3[0][0], &lB3[2][0], XB0, XB1, XA0, XA1)
    ITER( 7, 1, 0, &lB3[1][0], &lB3[0][0], XA0, XA1, XB0, XB1)
    ITER( 8, 0, 1, &lB3[2][0], &lB3[1][0], XB0, XB1, XA0, XA1)
    ITER( 9, 1, 0, &lB3[0][0], &lB3[2][0], XA0, XA1, XB0, XB1)
    ITER(10, 0, 1, &lB3[1][0], &lB3[0][0], XB0, XB1, XA0, XA1)
    ITER(11, 1, 0, &lB3[2][0], &lB3[1][0], XA0, XA1, XB0, XB1)
    ITER(12, 0, 1, &lB3[0][0], &lB3[2][0], XB0, XB1, XA0, XA1)
    ITER(13, 1, 0, &lB3[1][0], &lB3[0][0], XA0, XA1, XB0, XB1)
    ITER(14, 0, 1, &lB3[2][0], &lB3[1][0], XB0, XB1, XA0, XA1)
    ITER(15, 1, 0, &lB3[0][0], &lB3[2][0], XA0, XA1, XB0, XB1)

    // ---- ||x||^2: 4 staging threads per row ----
    x2p += __shfl_xor(x2p, 1); x2p += __shfl_xor(x2p, 2);
    if (q == 0) s_x2[R] = x2p;
    __syncthreads();

    // ---- epilogue: d2 -> q_unnorm (C/D: col=l15, row=lq*4+r) ----
    float c2a[4];
#pragma unroll
    for (int n = 0; n < 4; ++n) c2a[n] = wsC2[cg*64 + n*16 + l15];

#pragma unroll
    for (int m = 0; m < 4; ++m)
#pragma unroll
        for (int n = 0; n < 4; ++n)
#pragma unroll
            for (int r = 0; r < 4; ++r) {
                const int rw = rg*64 + m*16 + lq*4 + r;
                float d2 = fmaxf(s_x2[rw] + c2a[n] - 2.0f * acc[m][n][r], 0.0f);
                acc[m][n][r] = 1.0f / (1.0f + d2);
            }

    // ---- row sums: 16-lane shuffle, per-cg slot (deterministic) ----
#pragma unroll
    for (int m = 0; m < 4; ++m)
#pragma unroll
        for (int r = 0; r < 4; ++r) {
            float p = acc[m][0][r] + acc[m][1][r] + acc[m][2][r] + acc[m][3][r];
            p += __shfl_xor(p, 1); p += __shfl_xor(p, 2);
            p += __shfl_xor(p, 4); p += __shfl_xor(p, 8);
            if (l15 == 0) s_rs[cg][rg*64 + m*16 + lq*4 + r] = p;
        }
    __syncthreads();

    // ---- normalize + store ----
#pragma unroll
    for (int m = 0; m < 4; ++m)
#pragma unroll
        for (int r = 0; r < 4; ++r) {
            const int rw = rg*64 + m*16 + lq*4 + r;
            const float rinv = 1.0f / (s_rs[0][rw] + s_rs[1][rw] + s_rs[2][rw] + s_rs[3][rw]);
            float* o = out + (size_t)(row0 + rw) * KCL + cg*64 + l15;
#pragma unroll
            for (int n = 0; n < 4; ++n)
                o[n * 16] = acc[m][n][r] * rinv;
        }
}

extern "C" void kernel_launch(void* const* d_in, const int* in_sizes, int n_in,
                              void* d_out, int out_size, void* d_ws, size_t ws_size,
                              hipStream_t stream) {
    const float* x  = (const float*)d_in[0];
    const float* cl = (const float*)d_in[1];
    float* out = (float*)d_out;
    short* wsB  = (short*)d_ws;
    float* wsC2 = (float*)((char*)d_ws + (size_t)NTILES * BTILE * sizeof(short)); // +256 KB

    prep<<<80, 256, 0, stream>>>(cl, wsB, wsC2);
    const int B = in_sizes[0] / DDIM;     // 65536
    dec_main<<<B / BM, NT, 0, stream>>>(x, wsB, wsC2, out);
}